// Round 6
// baseline (329.631 us; speedup 1.0000x reference)
//
#include <hip/hip_runtime.h>
#include <hip/hip_bf16.h>

using f32x4  = __attribute__((ext_vector_type(4))) float;
using short8 = __attribute__((ext_vector_type(8))) short;
using u16    = unsigned short;
using u32    = unsigned int;

#define B_SZ   2
#define S_LEN  2048
#define NH     16
#define NKV    4
#define DH     64
#define DM     1024
#define NQKVC  1536
#define MROWS  4096
// 0.125 * log2(e): scores computed in log2 domain, softmax via exp2
#define QSCALE 0.18033688011112042f

__device__ __forceinline__ u16 f2bf(float f) {
  return __builtin_bit_cast(u16, __float2bfloat16(f));
}
__device__ __forceinline__ float bf2f(u16 b) {
  return __builtin_bit_cast(float, ((u32)b) << 16);
}
__device__ __forceinline__ void gld16(const void* g, void* l) {
  __builtin_amdgcn_global_load_lds((const __attribute__((address_space(1))) u32*)g,
                                   (__attribute__((address_space(3))) u32*)l, 16, 0, 0);
}

// ---------------- cast X fp32 -> bf16 ----------------
__global__ void k_cast_x(const float* __restrict__ x, u16* __restrict__ xb) {
  int i = (blockIdx.x * 256 + threadIdx.x) * 4;
  float4 v = *(const float4*)(x + i);
  ushort4 o;
  o.x = f2bf(v.x); o.y = f2bf(v.y); o.z = f2bf(v.z); o.w = f2bf(v.w);
  *(ushort4*)(xb + i) = o;
}

// ---------------- weight transpose: W[K=1024][ncols] fp32 -> Wt[n][1024] bf16 ----------------
__global__ void k_transpose_w(const float* __restrict__ w, int ncols, u16* __restrict__ wt) {
  __shared__ float t[32][33];
  int k0 = blockIdx.x * 32, n0 = blockIdx.y * 32;
  int tx = threadIdx.x, ty = threadIdx.y; // block (32,8)
#pragma unroll
  for (int j = 0; j < 32; j += 8)
    t[ty + j][tx] = w[(size_t)(k0 + ty + j) * ncols + n0 + tx];
  __syncthreads();
#pragma unroll
  for (int j = 0; j < 32; j += 8)
    wt[(size_t)(n0 + ty + j) * 1024 + k0 + tx] = f2bf(t[tx][ty + j]);
}

// ---------------- bias concat + trig tables ----------------
__global__ void k_prep_small(const float* __restrict__ bq, const float* __restrict__ bk,
                             const float* __restrict__ bv, const float* __restrict__ pe,
                             float* __restrict__ biasqkv, float* __restrict__ cs,
                             float* __restrict__ sn) {
  int i = blockIdx.x * 256 + threadIdx.x;
  if (i < NQKVC)
    biasqkv[i] = (i < 1024) ? bq[i] : (i < 1280 ? bk[i - 1024] : bv[i - 1280]);
  if (i < S_LEN * 32) {
    float a = pe[i];
    cs[i] = cosf(a);
    sn[i] = sinf(a);
  }
}

// ---------------- bf16 MFMA GEMM (m97-style global_load_lds staging) ----------------
template <typename OUT_T>
__global__ __launch_bounds__(256) void k_gemm(const u16* __restrict__ A,
                                              const u16* __restrict__ Bt,
                                              const float* __restrict__ bias,
                                              OUT_T* __restrict__ C,
                                              int M, int N, int K) {
  __shared__ u16 la[128 * 32];  // linear [128 rows][32 bf16], 64B rows
  __shared__ u16 lb[128 * 32];
  const int tid = threadIdx.x;
  const int m0 = blockIdx.x * 128, n0 = blockIdx.y * 128;
  const int lane = tid & 63, wv = tid >> 6;
  const int g = lane >> 4, lr = lane & 15;
  const int wr = wv >> 1, wc = wv & 1;

  // staging geometry: wave issues cover 16 rows x 64B each (64 lanes x 16B)
  const int srow0 = (wv * 2 + 0) * 16 + (lane >> 2);
  const int srow1 = (wv * 2 + 1) * 16 + (lane >> 2);
  const int scol = (lane & 3) * 8;  // u16 units
  const u16* pa0 = A  + (size_t)(m0 + srow0) * K + scol;
  const u16* pa1 = A  + (size_t)(m0 + srow1) * K + scol;
  const u16* pb0 = Bt + (size_t)(n0 + srow0) * K + scol;
  const u16* pb1 = Bt + (size_t)(n0 + srow1) * K + scol;
  u16* lda0 = &la[(wv * 2 + 0) * 512];
  u16* lda1 = &la[(wv * 2 + 1) * 512];
  u16* ldb0 = &lb[(wv * 2 + 0) * 512];
  u16* ldb1 = &lb[(wv * 2 + 1) * 512];

  f32x4 acc[4][4] = {};
  const int nk = K >> 5;
  for (int kt = 0; kt < nk; ++kt) {
    const int ko = kt * 32;
    gld16(pa0 + ko, lda0);
    gld16(pa1 + ko, lda1);
    gld16(pb0 + ko, ldb0);
    gld16(pb1 + ko, ldb1);
    __syncthreads();  // drains vmcnt; LDS tiles ready
    short8 af[4], bfr[4];
#pragma unroll
    for (int m = 0; m < 4; ++m)
      af[m] = *(const short8*)&la[(64 * wr + 16 * m + lr) * 32 + 8 * g];
#pragma unroll
    for (int n = 0; n < 4; ++n)
      bfr[n] = *(const short8*)&lb[(64 * wc + 16 * n + lr) * 32 + 8 * g];
#pragma unroll
    for (int m = 0; m < 4; ++m)
#pragma unroll
      for (int n = 0; n < 4; ++n)
        acc[m][n] = __builtin_amdgcn_mfma_f32_16x16x32_bf16(af[m], bfr[n], acc[m][n], 0, 0, 0);
    __syncthreads();  // all reads done before next stage overwrites
  }

#pragma unroll
  for (int m = 0; m < 4; ++m)
#pragma unroll
    for (int n = 0; n < 4; ++n) {
      const int col = n0 + 64 * wc + 16 * n + lr;
      const float bz = bias[col];
#pragma unroll
      for (int r = 0; r < 4; ++r) {
        const int row = m0 + 64 * wr + 16 * m + 4 * g + r;
        float v = acc[m][n][r] + bz;
        if constexpr (sizeof(OUT_T) == 2) C[(size_t)row * N + col] = f2bf(v);
        else                              C[(size_t)row * N + col] = v;
      }
    }
}

// ---------------- RoPE (Q scaled by QSCALE) + Q/K pack ----------------
// one block per (b,s) row; QKVp bf16 [4096][1536]
__global__ void k_rope_qk(const u16* __restrict__ p, const float* __restrict__ cs,
                          const float* __restrict__ sn, u16* __restrict__ Qr,
                          u16* __restrict__ Kr) {
  const int row = blockIdx.x;
  const int b = row >> 11, s = row & 2047;
  const u16* pr = p + (size_t)row * NQKVC;
  const float* crow = cs + s * 32;
  const float* srow = sn + s * 32;
  const int tid = threadIdx.x;
#pragma unroll
  for (int it = 0; it < 4; ++it) {
    int c = it * 256 + tid;
    int h = c >> 6, d = c & 63, j = d & 31;
    float x = bf2f(pr[c]);
    float y = bf2f(pr[c ^ 32]);
    float o = (x * crow[j] + (d < 32 ? -y : y) * srow[j]) * QSCALE;
    Qr[((size_t)(b * NH + h) * S_LEN + s) * DH + d] = f2bf(o);
  }
  {
    int c = 1024 + tid;
    int kvh = tid >> 6, d = tid & 63, j = d & 31;
    float x = bf2f(pr[c]);
    float y = bf2f(pr[c ^ 32]);
    float o = x * crow[j] + (d < 32 ? -y : y) * srow[j];
    Kr[((size_t)(b * NKV + kvh) * S_LEN + s) * DH + d] = f2bf(o);
  }
}

// ---------------- V pack: QKVp cols [1280,1536) -> Vt[B][Kv][64][S] (coalesced transpose) ----------------
__global__ void k_vpack(const u16* __restrict__ p, u16* __restrict__ Vt) {
  __shared__ u16 t[32][33];
  const int st = blockIdx.x * 32;  // s tile
  const int dt = blockIdx.y * 32;  // d tile
  const int bkv = blockIdx.z;
  const int b = bkv >> 2, kv = bkv & 3;
  const int tx = threadIdx.x, ty = threadIdx.y;  // (32,8)
#pragma unroll
  for (int j = 0; j < 32; j += 8)
    t[ty + j][tx] = p[(size_t)(b * S_LEN + st + ty + j) * NQKVC + 1280 + kv * 64 + dt + tx];
  __syncthreads();
#pragma unroll
  for (int j = 0; j < 32; j += 8)
    Vt[((size_t)(b * NKV + kv) * DH + dt + ty + j) * S_LEN + st + tx] = t[tx][ty + j];
}

// ---------------- causal GQA flash attention ----------------
// 2048 blocks x 128 threads (2 independent waves, no barriers).
// XCD-bijective swizzle: XCD j sees only bh in [4j, 4j+4) -> K/V 2MB per L2.
// Each wave owns 16 q rows (q = q0 + (lane&15)); scores/O lane-local per q.
__global__ __launch_bounds__(128, 4) void k_attn(const u16* __restrict__ Qr,
                                                 const u16* __restrict__ Kr,
                                                 const u16* __restrict__ Vt,
                                                 u16* __restrict__ Og) {
  __shared__ u16 plds[2][16][72];  // per-wave P[q16][key64], padded row stride
  const int tid = threadIdx.x, wv = tid >> 6, lane = tid & 63;
  const int g = lane >> 4, lr = lane & 15;
  // bijective XCD swizzle over 2048 blocks (8 XCDs x 256)
  const int wg = blockIdx.x;
  const int work = (wg & 7) * 256 + (wg >> 3);
  const int bh = work >> 6;   // 64 q-tiles per head
  const int qt = work & 63;   // 32-row q tile
  const int b = bh >> 4, h = bh & 15, kv = h >> 2;
  const int q0 = qt * 32 + wv * 16;

  const u16* Qbase = Qr + ((size_t)(b * NH + h) * S_LEN + q0) * DH;
  const u16* Kbase = Kr + (size_t)(b * NKV + kv) * S_LEN * DH;
  const u16* Vbase = Vt + (size_t)(b * NKV + kv) * DH * S_LEN;

  short8 qf0 = *(const short8*)(Qbase + lr * DH + 8 * g);       // d 0..31
  short8 qf1 = *(const short8*)(Qbase + lr * DH + 32 + 8 * g);  // d 32..63

  float m = -1e30f, l = 0.f;
  f32x4 accO[4] = {};   // O^T[d = 16t+4g+r][q = lr]
  const f32x4 z = {};
  u16* prow = &plds[wv][lr][0];

  const int myq = q0 + lr;
  const int kend = q0 + 16;  // keys [0, kend); tail keys masked causally
  for (int kb = 0; kb < kend; kb += 64) {
    // ---- K fragments ----
    short8 k0[4], k1[4];
#pragma unroll
    for (int t = 0; t < 4; ++t) {
      const u16* kp = Kbase + (size_t)(kb + 16 * t + lr) * DH;
      k0[t] = *(const short8*)(kp + 8 * g);
      k1[t] = *(const short8*)(kp + 32 + 8 * g);
    }
    // ---- V fragments for first key-half issued early (overlap softmax) ----
    short8 vf0[4];
#pragma unroll
    for (int t = 0; t < 4; ++t)
      vf0[t] = *(const short8*)(Vbase + (size_t)(16 * t + lr) * S_LEN + kb + 8 * g);

    // ---- QK^T (swapped: A=K rows=keys, B=Q cols=q) ----
    f32x4 s[4];
    __builtin_amdgcn_s_setprio(1);
#pragma unroll
    for (int t = 0; t < 4; ++t) {
      s[t] = __builtin_amdgcn_mfma_f32_16x16x32_bf16(k0[t], qf0, z, 0, 0, 0);
      s[t] = __builtin_amdgcn_mfma_f32_16x16x32_bf16(k1[t], qf1, s[t], 0, 0, 0);
    }
    __builtin_amdgcn_s_setprio(0);

    // ---- causal mask (diagonal block only; also covers the ragged tail) ----
    if (kb + 63 > q0) {
#pragma unroll
      for (int t = 0; t < 4; ++t)
#pragma unroll
        for (int r = 0; r < 4; ++r)
          if (kb + 16 * t + 4 * g + r > myq) s[t][r] = -1e30f;
    }
    // ---- online softmax (log2 domain), lane-local row ----
    float a0 = fmaxf(fmaxf(s[0][0], s[0][1]), fmaxf(s[0][2], s[0][3]));
    float a1 = fmaxf(fmaxf(s[1][0], s[1][1]), fmaxf(s[1][2], s[1][3]));
    float a2 = fmaxf(fmaxf(s[2][0], s[2][1]), fmaxf(s[2][2], s[2][3]));
    float a3 = fmaxf(fmaxf(s[3][0], s[3][1]), fmaxf(s[3][2], s[3][3]));
    float tm = fmaxf(fmaxf(a0, a1), fmaxf(a2, a3));
    tm = fmaxf(tm, __shfl_xor(tm, 16));
    tm = fmaxf(tm, __shfl_xor(tm, 32));
    if (__any(tm > m + 8.f)) {     // T13: defer rescale until max drifts > 8
      float mn = fmaxf(tm, m);
      float al = __builtin_exp2f(m - mn);
      m = mn;
      l *= al;
#pragma unroll
      for (int t = 0; t < 4; ++t) {
        accO[t][0] *= al; accO[t][1] *= al; accO[t][2] *= al; accO[t][3] *= al;
      }
    }
    float rs = 0.f;
#pragma unroll
    for (int t = 0; t < 4; ++t)
#pragma unroll
      for (int r = 0; r < 4; ++r) {
        float e = __builtin_exp2f(s[t][r] - m);
        s[t][r] = e;
        rs += e;
      }
    rs += __shfl_xor(rs, 16);
    rs += __shfl_xor(rs, 32);
    l += rs;
    // ---- P -> LDS (row q=lr, cols = keys), b64 writes ----
#pragma unroll
    for (int t = 0; t < 4; ++t) {
      u32 lo = (u32)f2bf(s[t][0]) | ((u32)f2bf(s[t][1]) << 16);
      u32 hi = (u32)f2bf(s[t][2]) | ((u32)f2bf(s[t][3]) << 16);
      uint2 w2; w2.x = lo; w2.y = hi;
      *(uint2*)(prow + 16 * t + 4 * g) = w2;
    }
    // ---- PV (swapped: A=V^T rows=d, B=P^T cols=q) ----
    short8 pb0 = *(const short8*)(prow + 8 * g);
    __builtin_amdgcn_s_setprio(1);
#pragma unroll
    for (int t = 0; t < 4; ++t)
      accO[t] = __builtin_amdgcn_mfma_f32_16x16x32_bf16(vf0[t], pb0, accO[t], 0, 0, 0);
    __builtin_amdgcn_s_setprio(0);
    short8 pb1 = *(const short8*)(prow + 32 + 8 * g);
    __builtin_amdgcn_s_setprio(1);
#pragma unroll
    for (int t = 0; t < 4; ++t) {
      short8 vf = *(const short8*)(Vbase + (size_t)(16 * t + lr) * S_LEN + kb + 32 + 8 * g);
      accO[t] = __builtin_amdgcn_mfma_f32_16x16x32_bf16(vf, pb1, accO[t], 0, 0, 0);
    }
    __builtin_amdgcn_s_setprio(0);
  }

  const float inv = 1.0f / l;
  u16* orow = Og + ((size_t)(b * S_LEN + q0 + lr)) * DM + h * DH;
#pragma unroll
  for (int t = 0; t < 4; ++t) {
    ushort4 o;
    o.x = f2bf(accO[t][0] * inv);
    o.y = f2bf(accO[t][1] * inv);
    o.z = f2bf(accO[t][2] * inv);
    o.w = f2bf(accO[t][3] * inv);
    *(ushort4*)(orow + 16 * t + 4 * g) = o;
  }
}

extern "C" void kernel_launch(void* const* d_in, const int* in_sizes, int n_in,
                              void* d_out, int out_size, void* d_ws, size_t ws_size,
                              hipStream_t stream) {
  const float* x  = (const float*)d_in[0];
  const float* pe = (const float*)d_in[1];
  const float* Wq = (const float*)d_in[2];
  const float* bq = (const float*)d_in[3];
  const float* Wk = (const float*)d_in[4];
  const float* bk = (const float*)d_in[5];
  const float* Wv = (const float*)d_in[6];
  const float* bv = (const float*)d_in[7];
  const float* Wo = (const float*)d_in[8];
  const float* bo = (const float*)d_in[9];
  float* out = (float*)d_out;

  char* w = (char*)d_ws;
  u16* Xb      = (u16*)w;   w += (size_t)MROWS * DM * 2;
  u16* Wqkvt   = (u16*)w;   w += (size_t)NQKVC * DM * 2;
  u16* Wot     = (u16*)w;   w += (size_t)DM * DM * 2;
  float* biasq = (float*)w; w += NQKVC * 4;
  float* cs    = (float*)w; w += S_LEN * 32 * 4;
  float* sn    = (float*)w; w += S_LEN * 32 * 4;
  u16* QKVp    = (u16*)w;   w += (size_t)MROWS * NQKVC * 2;
  u16* Qr      = (u16*)w;   w += (size_t)B_SZ * NH * S_LEN * DH * 2;
  u16* Kr      = (u16*)w;   w += (size_t)B_SZ * NKV * S_LEN * DH * 2;
  u16* Vt      = (u16*)w;   w += (size_t)B_SZ * NKV * DH * S_LEN * 2;
  u16* Og      = (u16*)w;

  dim3 tb(32, 8);
  k_cast_x<<<MROWS * DM / (256 * 4), 256, 0, stream>>>(x, Xb);
  k_transpose_w<<<dim3(32, 32), tb, 0, stream>>>(Wq, 1024, Wqkvt);
  k_transpose_w<<<dim3(32, 8),  tb, 0, stream>>>(Wk, 256,  Wqkvt + (size_t)1024 * 1024);
  k_transpose_w<<<dim3(32, 8),  tb, 0, stream>>>(Wv, 256,  Wqkvt + (size_t)1280 * 1024);
  k_transpose_w<<<dim3(32, 32), tb, 0, stream>>>(Wo, 1024, Wot);
  k_prep_small<<<(S_LEN * 32 + 255) / 256, 256, 0, stream>>>(bq, bk, bv, pe, biasq, cs, sn);

  k_gemm<u16><<<dim3(MROWS / 128, NQKVC / 128), 256, 0, stream>>>(
      Xb, Wqkvt, biasq, QKVp, MROWS, NQKVC, DM);

  k_rope_qk<<<MROWS, 256, 0, stream>>>(QKVp, cs, sn, Qr, Kr);
  k_vpack<<<dim3(S_LEN / 32, DH / 32, B_SZ * NKV), tb, 0, stream>>>(QKVp, Vt);

  k_attn<<<2048, 128, 0, stream>>>(Qr, Kr, Vt, Og);

  k_gemm<float><<<dim3(MROWS / 128, DM / 128), 256, 0, stream>>>(
      Og, Wot, bo, out, MROWS, DM, DM);
}

// Round 8
// 214.459 us; speedup vs baseline: 1.5370x; 1.5370x over previous
//
#include <hip/hip_runtime.h>
#include <hip/hip_bf16.h>

using f32x4  = __attribute__((ext_vector_type(4))) float;
using short8 = __attribute__((ext_vector_type(8))) short;
using u16    = unsigned short;
using u32    = unsigned int;

#define B_SZ   2
#define S_LEN  2048
#define NH     16
#define NKV    4
#define DH     64
#define DM     1024
#define NQKVC  1536
#define MROWS  4096
// 0.125 * log2(e): scores computed in log2 domain, softmax via exp2
#define QSCALE 0.18033688011112042f

__device__ __forceinline__ u16 f2bf(float f) {
  return __builtin_bit_cast(u16, __float2bfloat16(f));
}
__device__ __forceinline__ float bf2f(u16 b) {
  return __builtin_bit_cast(float, ((u32)b) << 16);
}
__device__ __forceinline__ void gld16(const void* g, void* l) {
  __builtin_amdgcn_global_load_lds((const __attribute__((address_space(1))) u32*)g,
                                   (__attribute__((address_space(3))) u32*)l, 16, 0, 0);
}

// ---------------- cast X fp32 -> bf16 ----------------
__global__ void k_cast_x(const float* __restrict__ x, u16* __restrict__ xb) {
  int i = (blockIdx.x * 256 + threadIdx.x) * 4;
  float4 v = *(const float4*)(x + i);
  ushort4 o;
  o.x = f2bf(v.x); o.y = f2bf(v.y); o.z = f2bf(v.z); o.w = f2bf(v.w);
  *(ushort4*)(xb + i) = o;
}

// ---------------- weight transpose: W[K=1024][ncols] fp32 -> Wt[n][1024] bf16 ----------------
__global__ void k_transpose_w(const float* __restrict__ w, int ncols, u16* __restrict__ wt) {
  __shared__ float t[32][33];
  int k0 = blockIdx.x * 32, n0 = blockIdx.y * 32;
  int tx = threadIdx.x, ty = threadIdx.y; // block (32,8)
#pragma unroll
  for (int j = 0; j < 32; j += 8)
    t[ty + j][tx] = w[(size_t)(k0 + ty + j) * ncols + n0 + tx];
  __syncthreads();
#pragma unroll
  for (int j = 0; j < 32; j += 8)
    wt[(size_t)(n0 + ty + j) * 1024 + k0 + tx] = f2bf(t[tx][ty + j]);
}

// ---------------- bias concat + trig tables ----------------
__global__ void k_prep_small(const float* __restrict__ bq, const float* __restrict__ bk,
                             const float* __restrict__ bv, const float* __restrict__ pe,
                             float* __restrict__ biasqkv, float* __restrict__ cs,
                             float* __restrict__ sn) {
  int i = blockIdx.x * 256 + threadIdx.x;
  if (i < NQKVC)
    biasqkv[i] = (i < 1024) ? bq[i] : (i < 1280 ? bk[i - 1024] : bv[i - 1280]);
  if (i < S_LEN * 32) {
    float a = pe[i];
    cs[i] = cosf(a);
    sn[i] = sinf(a);
  }
}

// ---------------- bf16 MFMA GEMM (m97-style global_load_lds staging) ----------------
template <typename OUT_T>
__global__ __launch_bounds__(256) void k_gemm(const u16* __restrict__ A,
                                              const u16* __restrict__ Bt,
                                              const float* __restrict__ bias,
                                              OUT_T* __restrict__ C,
                                              int M, int N, int K) {
  __shared__ u16 la[128 * 32];  // linear [128 rows][32 bf16], 64B rows
  __shared__ u16 lb[128 * 32];
  const int tid = threadIdx.x;
  const int m0 = blockIdx.x * 128, n0 = blockIdx.y * 128;
  const int lane = tid & 63, wv = tid >> 6;
  const int g = lane >> 4, lr = lane & 15;
  const int wr = wv >> 1, wc = wv & 1;

  const int srow0 = (wv * 2 + 0) * 16 + (lane >> 2);
  const int srow1 = (wv * 2 + 1) * 16 + (lane >> 2);
  const int scol = (lane & 3) * 8;  // u16 units
  const u16* pa0 = A  + (size_t)(m0 + srow0) * K + scol;
  const u16* pa1 = A  + (size_t)(m0 + srow1) * K + scol;
  const u16* pb0 = Bt + (size_t)(n0 + srow0) * K + scol;
  const u16* pb1 = Bt + (size_t)(n0 + srow1) * K + scol;
  u16* lda0 = &la[(wv * 2 + 0) * 512];
  u16* lda1 = &la[(wv * 2 + 1) * 512];
  u16* ldb0 = &lb[(wv * 2 + 0) * 512];
  u16* ldb1 = &lb[(wv * 2 + 1) * 512];

  f32x4 acc[4][4] = {};
  const int nk = K >> 5;
  for (int kt = 0; kt < nk; ++kt) {
    const int ko = kt * 32;
    gld16(pa0 + ko, lda0);
    gld16(pa1 + ko, lda1);
    gld16(pb0 + ko, ldb0);
    gld16(pb1 + ko, ldb1);
    __syncthreads();
    short8 af[4], bfr[4];
#pragma unroll
    for (int m = 0; m < 4; ++m)
      af[m] = *(const short8*)&la[(64 * wr + 16 * m + lr) * 32 + 8 * g];
#pragma unroll
    for (int n = 0; n < 4; ++n)
      bfr[n] = *(const short8*)&lb[(64 * wc + 16 * n + lr) * 32 + 8 * g];
#pragma unroll
    for (int m = 0; m < 4; ++m)
#pragma unroll
      for (int n = 0; n < 4; ++n)
        acc[m][n] = __builtin_amdgcn_mfma_f32_16x16x32_bf16(af[m], bfr[n], acc[m][n], 0, 0, 0);
    __syncthreads();
  }

#pragma unroll
  for (int m = 0; m < 4; ++m)
#pragma unroll
    for (int n = 0; n < 4; ++n) {
      const int col = n0 + 64 * wc + 16 * n + lr;
      const float bz = bias[col];
#pragma unroll
      for (int r = 0; r < 4; ++r) {
        const int row = m0 + 64 * wr + 16 * m + 4 * g + r;
        float v = acc[m][n][r] + bz;
        if constexpr (sizeof(OUT_T) == 2) C[(size_t)row * N + col] = f2bf(v);
        else                              C[(size_t)row * N + col] = v;
      }
    }
}

// ---------------- RoPE (Q scaled by QSCALE) + Q/K pack ----------------
__global__ void k_rope_qk(const u16* __restrict__ p, const float* __restrict__ cs,
                          const float* __restrict__ sn, u16* __restrict__ Qr,
                          u16* __restrict__ Kr) {
  const int row = blockIdx.x;
  const int b = row >> 11, s = row & 2047;
  const u16* pr = p + (size_t)row * NQKVC;
  const float* crow = cs + s * 32;
  const float* srow = sn + s * 32;
  const int tid = threadIdx.x;
#pragma unroll
  for (int it = 0; it < 4; ++it) {
    int c = it * 256 + tid;
    int h = c >> 6, d = c & 63, j = d & 31;
    float x = bf2f(pr[c]);
    float y = bf2f(pr[c ^ 32]);
    float o = (x * crow[j] + (d < 32 ? -y : y) * srow[j]) * QSCALE;
    Qr[((size_t)(b * NH + h) * S_LEN + s) * DH + d] = f2bf(o);
  }
  {
    int c = 1024 + tid;
    int kvh = tid >> 6, d = tid & 63, j = d & 31;
    float x = bf2f(pr[c]);
    float y = bf2f(pr[c ^ 32]);
    float o = x * crow[j] + (d < 32 ? -y : y) * srow[j];
    Kr[((size_t)(b * NKV + kvh) * S_LEN + s) * DH + d] = f2bf(o);
  }
}

// ---------------- V pack: QKVp cols [1280,1536) -> Vt[B][Kv][64][S] ----------------
__global__ void k_vpack(const u16* __restrict__ p, u16* __restrict__ Vt) {
  __shared__ u16 t[32][33];
  const int st = blockIdx.x * 32;
  const int dt = blockIdx.y * 32;
  const int bkv = blockIdx.z;
  const int b = bkv >> 2, kv = bkv & 3;
  const int tx = threadIdx.x, ty = threadIdx.y;  // (32,8)
#pragma unroll
  for (int j = 0; j < 32; j += 8)
    t[ty + j][tx] = p[(size_t)(b * S_LEN + st + ty + j) * NQKVC + 1280 + kv * 64 + dt + tx];
  __syncthreads();
#pragma unroll
  for (int j = 0; j < 32; j += 8)
    Vt[((size_t)(b * NKV + kv) * DH + dt + ty + j) * S_LEN + st + tx] = t[tx][ty + j];
}

// ---------------- causal GQA flash attention, LDS-staged K/V ----------------
// 512 blocks x 256 threads (4 waves). Block covers 64 q-rows; processes q-tile
// pair (qt, 31-qt) sequentially -> uniform 33 k-tiles/block. 2 blocks/CU.
// K/V tiles (64x64 bf16) staged once per block via global_load_lds with
// XOR-swizzled SOURCE (rule #21): lds[row][c] holds global chunk c^(row&7).
// ds_read applies the same XOR -> ~2-way bank aliasing (free).
__global__ __launch_bounds__(256, 2) void k_attn(const u16* __restrict__ Qr,
                                                 const u16* __restrict__ Kr,
                                                 const u16* __restrict__ Vt,
                                                 u16* __restrict__ Og) {
  __shared__ u16 kbuf[2][4096];   // [64 rows][8 chunks of 8 bf16], swizzled
  __shared__ u16 vbuf[2][4096];   // V^T: [64 d][8 chunks], swizzled
  __shared__ u16 plds[4][16][72]; // per-wave P[q16][key64], padded

  const int tid = threadIdx.x, wv = tid >> 6, lane = tid & 63;
  const int g = lane >> 4, lr = lane & 15;
  // XCD-bijective mapping: 8 XCDs x 64 works; per XCD 4 bh x 16 pairs
  const int wg = blockIdx.x;
  const int xcd = wg & 7, iw = wg >> 3;
  const int bh = xcd * 4 + (iw & 3);
  const int pr = iw >> 2;                 // 0..15
  const int b = bh >> 4, h = bh & 15, kv = h >> 2;

  const u16* Kbase = Kr + (size_t)(b * NKV + kv) * S_LEN * DH;
  const u16* Vbase = Vt + (size_t)(b * NKV + kv) * DH * S_LEN;

  // staging geometry (per thread): two issues cover rows 0..31 / 32..63
  const int sr = tid >> 3;            // row 0..31
  const int sc = tid & 7;             // chunk-in-row
  const int ssw = sc ^ (sr & 7);      // swizzled source chunk ((sr+32)&7 == sr&7)
  const int rsw = lr & 7;             // consume-side row swizzle
  u16* prow = &plds[wv][lr][0];

  for (int pass = 0; pass < 2; ++pass) {
    const int qt = pass ? (31 - pr) : pr;
    const int Q0 = qt * 64;
    const int q0w = Q0 + wv * 16;
    const int myq = q0w + lr;

    const u16* Qb = Qr + ((size_t)(b * NH + h) * S_LEN + q0w) * DH;
    short8 qf0 = *(const short8*)(Qb + lr * DH + 8 * g);
    short8 qf1 = *(const short8*)(Qb + lr * DH + 32 + 8 * g);

    float m = -1e30f, l = 0.f;
    f32x4 accO[4] = {};
    const f32x4 z = {};

    const int nt = qt + 1;  // 64-key tiles
    // prologue: stage tile 0 into buf 0
    {
      gld16(Kbase + (size_t)sr * DH + ssw * 8,        &kbuf[0][wv * 512]);
      gld16(Kbase + (size_t)(sr + 32) * DH + ssw * 8, &kbuf[0][2048 + wv * 512]);
      gld16(Vbase + (size_t)sr * S_LEN + ssw * 8,        &vbuf[0][wv * 512]);
      gld16(Vbase + (size_t)(sr + 32) * S_LEN + ssw * 8, &vbuf[0][2048 + wv * 512]);
    }
    __syncthreads();
    int buf = 0;
    for (int ti = 0; ti < nt; ++ti) {
      const int kb = ti * 64;
      if (ti + 1 < nt) {  // prefetch next tile into other buffer
        const int kn = kb + 64;
        gld16(Kbase + (size_t)(kn + sr) * DH + ssw * 8,      &kbuf[buf ^ 1][wv * 512]);
        gld16(Kbase + (size_t)(kn + sr + 32) * DH + ssw * 8, &kbuf[buf ^ 1][2048 + wv * 512]);
        gld16(Vbase + (size_t)sr * S_LEN + kn + ssw * 8,        &vbuf[buf ^ 1][wv * 512]);
        gld16(Vbase + (size_t)(sr + 32) * S_LEN + kn + ssw * 8, &vbuf[buf ^ 1][2048 + wv * 512]);
      }
      const u16* kl = kbuf[buf];
      const u16* vl = vbuf[buf];
      // ---- K fragments from LDS (swizzled read) ----
      short8 k0[4], k1[4];
#pragma unroll
      for (int t = 0; t < 4; ++t) {
        const int row = 16 * t + lr;
        k0[t] = *(const short8*)&kl[row * 64 + (g ^ rsw) * 8];
        k1[t] = *(const short8*)&kl[row * 64 + ((4 + g) ^ rsw) * 8];
      }
      // ---- QK^T (swapped: A=K rows=keys, B=Q cols=q) ----
      f32x4 s[4];
      __builtin_amdgcn_s_setprio(1);
#pragma unroll
      for (int t = 0; t < 4; ++t) {
        s[t] = __builtin_amdgcn_mfma_f32_16x16x32_bf16(k0[t], qf0, z, 0, 0, 0);
        s[t] = __builtin_amdgcn_mfma_f32_16x16x32_bf16(k1[t], qf1, s[t], 0, 0, 0);
      }
      __builtin_amdgcn_s_setprio(0);
      // ---- causal mask (diagonal tile only) ----
      if (kb + 63 > q0w) {
#pragma unroll
        for (int t = 0; t < 4; ++t)
#pragma unroll
          for (int r = 0; r < 4; ++r)
            if (kb + 16 * t + 4 * g + r > myq) s[t][r] = -1e30f;
      }
      // ---- online softmax (log2 domain), lane-local row ----
      float a0 = fmaxf(fmaxf(s[0][0], s[0][1]), fmaxf(s[0][2], s[0][3]));
      float a1 = fmaxf(fmaxf(s[1][0], s[1][1]), fmaxf(s[1][2], s[1][3]));
      float a2 = fmaxf(fmaxf(s[2][0], s[2][1]), fmaxf(s[2][2], s[2][3]));
      float a3 = fmaxf(fmaxf(s[3][0], s[3][1]), fmaxf(s[3][2], s[3][3]));
      float tm = fmaxf(fmaxf(a0, a1), fmaxf(a2, a3));
      tm = fmaxf(tm, __shfl_xor(tm, 16));
      tm = fmaxf(tm, __shfl_xor(tm, 32));
      if (__any(tm > m + 8.f)) {   // T13 defer-rescale
        float mn = fmaxf(tm, m);
        float al = __builtin_exp2f(m - mn);
        m = mn;
        l *= al;
#pragma unroll
        for (int t = 0; t < 4; ++t) {
          accO[t][0] *= al; accO[t][1] *= al; accO[t][2] *= al; accO[t][3] *= al;
        }
      }
      float rs = 0.f;
#pragma unroll
      for (int t = 0; t < 4; ++t)
#pragma unroll
        for (int r = 0; r < 4; ++r) {
          float e = __builtin_exp2f(s[t][r] - m);
          s[t][r] = e;
          rs += e;
        }
      rs += __shfl_xor(rs, 16);
      rs += __shfl_xor(rs, 32);
      l += rs;
      // ---- P -> LDS (row q=lr), b64 writes ----
#pragma unroll
      for (int t = 0; t < 4; ++t) {
        u32 lo = (u32)f2bf(s[t][0]) | ((u32)f2bf(s[t][1]) << 16);
        u32 hi = (u32)f2bf(s[t][2]) | ((u32)f2bf(s[t][3]) << 16);
        uint2 w2; w2.x = lo; w2.y = hi;
        *(uint2*)(prow + 16 * t + 4 * g) = w2;
      }
      // ---- PV (A=V^T rows=d, B=P^T cols=q), V from swizzled LDS ----
      short8 pb0 = *(const short8*)(prow + 8 * g);
      short8 pb1 = *(const short8*)(prow + 32 + 8 * g);
      __builtin_amdgcn_s_setprio(1);
#pragma unroll
      for (int t = 0; t < 4; ++t) {
        const int row = 16 * t + lr;
        short8 vf0 = *(const short8*)&vl[row * 64 + (g ^ rsw) * 8];
        short8 vf1 = *(const short8*)&vl[row * 64 + ((4 + g) ^ rsw) * 8];
        accO[t] = __builtin_amdgcn_mfma_f32_16x16x32_bf16(vf0, pb0, accO[t], 0, 0, 0);
        accO[t] = __builtin_amdgcn_mfma_f32_16x16x32_bf16(vf1, pb1, accO[t], 0, 0, 0);
      }
      __builtin_amdgcn_s_setprio(0);
      __syncthreads();   // staged next tile arrived; all reads of buf done
      buf ^= 1;
    }

    const float inv = 1.0f / l;
    u16* orow = Og + ((size_t)(b * S_LEN + q0w + lr)) * DM + h * DH;
#pragma unroll
    for (int t = 0; t < 4; ++t) {
      ushort4 o;
      o.x = f2bf(accO[t][0] * inv);
      o.y = f2bf(accO[t][1] * inv);
      o.z = f2bf(accO[t][2] * inv);
      o.w = f2bf(accO[t][3] * inv);
      *(ushort4*)(orow + 16 * t + 4 * g) = o;
    }
    __syncthreads();  // pass boundary: stores done before re-staging
  }
}

extern "C" void kernel_launch(void* const* d_in, const int* in_sizes, int n_in,
                              void* d_out, int out_size, void* d_ws, size_t ws_size,
                              hipStream_t stream) {
  const float* x  = (const float*)d_in[0];
  const float* pe = (const float*)d_in[1];
  const float* Wq = (const float*)d_in[2];
  const float* bq = (const float*)d_in[3];
  const float* Wk = (const float*)d_in[4];
  const float* bk = (const float*)d_in[5];
  const float* Wv = (const float*)d_in[6];
  const float* bv = (const float*)d_in[7];
  const float* Wo = (const float*)d_in[8];
  const float* bo = (const float*)d_in[9];
  float* out = (float*)d_out;

  char* w = (char*)d_ws;
  u16* Xb      = (u16*)w;   w += (size_t)MROWS * DM * 2;
  u16* Wqkvt   = (u16*)w;   w += (size_t)NQKVC * DM * 2;
  u16* Wot     = (u16*)w;   w += (size_t)DM * DM * 2;
  float* biasq = (float*)w; w += NQKVC * 4;
  float* cs    = (float*)w; w += S_LEN * 32 * 4;
  float* sn    = (float*)w; w += S_LEN * 32 * 4;
  u16* QKVp    = (u16*)w;   w += (size_t)MROWS * NQKVC * 2;
  u16* Qr      = (u16*)w;   w += (size_t)B_SZ * NH * S_LEN * DH * 2;
  u16* Kr      = (u16*)w;   w += (size_t)B_SZ * NKV * S_LEN * DH * 2;
  u16* Vt      = (u16*)w;   w += (size_t)B_SZ * NKV * DH * S_LEN * 2;
  u16* Og      = (u16*)w;

  dim3 tb(32, 8);
  k_cast_x<<<MROWS * DM / (256 * 4), 256, 0, stream>>>(x, Xb);
  k_transpose_w<<<dim3(32, 32), tb, 0, stream>>>(Wq, 1024, Wqkvt);
  k_transpose_w<<<dim3(32, 8),  tb, 0, stream>>>(Wk, 256,  Wqkvt + (size_t)1024 * 1024);
  k_transpose_w<<<dim3(32, 8),  tb, 0, stream>>>(Wv, 256,  Wqkvt + (size_t)1280 * 1024);
  k_transpose_w<<<dim3(32, 32), tb, 0, stream>>>(Wo, 1024, Wot);
  k_prep_small<<<(S_LEN * 32 + 255) / 256, 256, 0, stream>>>(bq, bk, bv, pe, biasq, cs, sn);

  k_gemm<u16><<<dim3(MROWS / 128, NQKVC / 128), 256, 0, stream>>>(
      Xb, Wqkvt, biasq, QKVp, MROWS, NQKVC, DM);

  k_rope_qk<<<MROWS, 256, 0, stream>>>(QKVp, cs, sn, Qr, Kr);
  k_vpack<<<dim3(S_LEN / 32, DH / 32, B_SZ * NKV), tb, 0, stream>>>(QKVp, Vt);

  k_attn<<<512, 256, 0, stream>>>(Qr, Kr, Vt, Og);

  k_gemm<float><<<dim3(MROWS / 128, DM / 128), 256, 0, stream>>>(
      Og, Wot, bo, out, MROWS, DM, DM);
}

// Round 11
// 187.242 us; speedup vs baseline: 1.7605x; 1.1454x over previous
//
#include <hip/hip_runtime.h>
#include <hip/hip_bf16.h>

using f32x4  = __attribute__((ext_vector_type(4))) float;
using short8 = __attribute__((ext_vector_type(8))) short;
using u16    = unsigned short;
using u32    = unsigned int;

#define B_SZ   2
#define S_LEN  2048
#define NH     16
#define NKV    4
#define DH     64
#define DM     1024
#define NQKVC  1536
#define MROWS  4096
// 0.125 * log2(e): scores computed in log2 domain, softmax via exp2
#define QSCALE 0.18033688011112042f

__device__ __forceinline__ u16 f2bf(float f) {
  return __builtin_bit_cast(u16, __float2bfloat16(f));
}
__device__ __forceinline__ float bf2f(u16 b) {
  return __builtin_bit_cast(float, ((u32)b) << 16);
}
__device__ __forceinline__ void gld16(const void* g, void* l) {
  __builtin_amdgcn_global_load_lds((const __attribute__((address_space(1))) u32*)g,
                                   (__attribute__((address_space(3))) u32*)l, 16, 0, 0);
}

// ---------------- fused prep: cast X, transpose 4 weights, bias+trig ----------------
__device__ __forceinline__ void transp_tile(const float* __restrict__ w, int ncols,
                                            u16* __restrict__ wt, int bx, int by,
                                            int tid, float (*t)[33]) {
  const int k0 = bx * 32, n0 = by * 32;
  const int tx = tid & 31, ty = tid >> 5;
#pragma unroll
  for (int j = 0; j < 32; j += 8)
    t[ty + j][tx] = w[(size_t)(k0 + ty + j) * ncols + n0 + tx];
  __syncthreads();
#pragma unroll
  for (int j = 0; j < 32; j += 8)
    wt[(size_t)(n0 + ty + j) * 1024 + k0 + tx] = f2bf(t[tx][ty + j]);
}

__global__ __launch_bounds__(256) void k_prep(
    const float* __restrict__ x, u16* __restrict__ xb,
    const float* __restrict__ Wq, const float* __restrict__ Wk,
    const float* __restrict__ Wv, const float* __restrict__ Wo,
    u16* __restrict__ Wqkvt, u16* __restrict__ Wot,
    const float* __restrict__ bq, const float* __restrict__ bk,
    const float* __restrict__ bv, const float* __restrict__ pe,
    float* __restrict__ biasqkv, float* __restrict__ cs, float* __restrict__ sn) {
  __shared__ float tt[32][33];
  const int job = blockIdx.x, tid = threadIdx.x;
  if (job < 1024) {                       // cast X fp32->bf16: 4096 floats/job
#pragma unroll
    for (int u = 0; u < 4; ++u) {
      int i = job * 4096 + u * 1024 + tid * 4;
      float4 v = *(const float4*)(x + i);
      ushort4 o;
      o.x = f2bf(v.x); o.y = f2bf(v.y); o.z = f2bf(v.z); o.w = f2bf(v.w);
      *(ushort4*)(xb + i) = o;
    }
  } else if (job < 2048) {                // Wq^T
    int t = job - 1024;
    transp_tile(Wq, 1024, Wqkvt, t & 31, t >> 5, tid, tt);
  } else if (job < 2304) {                // Wk^T
    int t = job - 2048;
    transp_tile(Wk, 256, Wqkvt + (size_t)1024 * 1024, t & 31, t >> 5, tid, tt);
  } else if (job < 2560) {                // Wv^T
    int t = job - 2304;
    transp_tile(Wv, 256, Wqkvt + (size_t)1280 * 1024, t & 31, t >> 5, tid, tt);
  } else if (job < 3584) {                // Wo^T
    int t = job - 2560;
    transp_tile(Wo, 1024, Wot, t & 31, t >> 5, tid, tt);
  } else {                                // bias concat + trig tables
    int i = (job - 3584) * 256 + tid;
    if (i < NQKVC)
      biasqkv[i] = (i < 1024) ? bq[i] : (i < 1280 ? bk[i - 1024] : bv[i - 1280]);
    float a = pe[i];
    cs[i] = cosf(a);
    sn[i] = sinf(a);
  }
}

// ---------------- bf16 MFMA GEMM, 128x64 tile (3/2 blocks per CU) ----------------
template <typename OUT_T>
__global__ __launch_bounds__(256) void k_gemm(const u16* __restrict__ A,
                                              const u16* __restrict__ Bt,
                                              const float* __restrict__ bias,
                                              OUT_T* __restrict__ C,
                                              int M, int N, int K) {
  __shared__ u16 la[128 * 32];  // linear [128 rows][32 bf16]
  __shared__ u16 lb[64 * 32];
  const int tid = threadIdx.x;
  const int m0 = blockIdx.x * 128, n0 = blockIdx.y * 64;
  const int lane = tid & 63, wv = tid >> 6;
  const int g = lane >> 4, lr = lane & 15;
  const int wr = wv >> 1, wc = wv & 1;

  const int sr = tid >> 2;           // row 0..63
  const int scol = (tid & 3) * 8;    // u16 units
  const u16* pa0 = A  + (size_t)(m0 + sr) * K + scol;
  const u16* pa1 = A  + (size_t)(m0 + 64 + sr) * K + scol;
  const u16* pb  = Bt + (size_t)(n0 + sr) * K + scol;
  u16* lda0 = &la[wv * 512];
  u16* lda1 = &la[2048 + wv * 512];
  u16* ldb  = &lb[wv * 512];

  f32x4 acc[4][2] = {};
  const int nk = K >> 5;
  for (int kt = 0; kt < nk; ++kt) {
    const int ko = kt * 32;
    gld16(pa0 + ko, lda0);
    gld16(pa1 + ko, lda1);
    gld16(pb + ko, ldb);
    __syncthreads();
    short8 af[4], bfr[2];
#pragma unroll
    for (int m = 0; m < 4; ++m)
      af[m] = *(const short8*)&la[(64 * wr + 16 * m + lr) * 32 + 8 * g];
#pragma unroll
    for (int n = 0; n < 2; ++n)
      bfr[n] = *(const short8*)&lb[(32 * wc + 16 * n + lr) * 32 + 8 * g];
#pragma unroll
    for (int m = 0; m < 4; ++m)
#pragma unroll
      for (int n = 0; n < 2; ++n)
        acc[m][n] = __builtin_amdgcn_mfma_f32_16x16x32_bf16(af[m], bfr[n], acc[m][n], 0, 0, 0);
    __syncthreads();
  }

#pragma unroll
  for (int m = 0; m < 4; ++m)
#pragma unroll
    for (int n = 0; n < 2; ++n) {
      const int col = n0 + 32 * wc + 16 * n + lr;
      const float bz = bias[col];
#pragma unroll
      for (int r = 0; r < 4; ++r) {
        const int row = m0 + 64 * wr + 16 * m + 4 * g + r;
        float v = acc[m][n][r] + bz;
        if constexpr (sizeof(OUT_T) == 2) C[(size_t)row * N + col] = f2bf(v);
        else                              C[(size_t)row * N + col] = v;
      }
    }
}

// ---------------- fused RoPE Q/K pack + V transpose pack ----------------
__global__ __launch_bounds__(256) void k_rv(const u16* __restrict__ p,
                                            const float* __restrict__ cs,
                                            const float* __restrict__ sn,
                                            u16* __restrict__ Qr, u16* __restrict__ Kr,
                                            u16* __restrict__ Vt) {
  __shared__ u16 tt[32][33];
  const int job = blockIdx.x, tid = threadIdx.x;
  if (job < 4096) {   // RoPE + Q/K pack, one (b,s) row per block
    const int row = job;
    const int b = row >> 11, s = row & 2047;
    const u16* pr = p + (size_t)row * NQKVC;
    const float* crow = cs + s * 32;
    const float* srow = sn + s * 32;
#pragma unroll
    for (int it = 0; it < 4; ++it) {
      int c = it * 256 + tid;
      int h = c >> 6, d = c & 63, j = d & 31;
      float x = bf2f(pr[c]);
      float y = bf2f(pr[c ^ 32]);
      float o = (x * crow[j] + (d < 32 ? -y : y) * srow[j]) * QSCALE;
      Qr[((size_t)(b * NH + h) * S_LEN + s) * DH + d] = f2bf(o);
    }
    {
      int c = 1024 + tid;
      int kvh = tid >> 6, d = tid & 63, j = d & 31;
      float x = bf2f(pr[c]);
      float y = bf2f(pr[c ^ 32]);
      float o = x * crow[j] + (d < 32 ? -y : y) * srow[j];
      Kr[((size_t)(b * NKV + kvh) * S_LEN + s) * DH + d] = f2bf(o);
    }
  } else {            // V transpose pack
    const int idx = job - 4096;        // 0..1023
    const int st = (idx & 63) * 32;
    const int dt = ((idx >> 6) & 1) * 32;
    const int bkv = idx >> 7;
    const int b = bkv >> 2, kv = bkv & 3;
    const int tx = tid & 31, ty = tid >> 5;
#pragma unroll
    for (int j = 0; j < 32; j += 8)
      tt[ty + j][tx] = p[(size_t)(b * S_LEN + st + ty + j) * NQKVC + 1280 + kv * 64 + dt + tx];
    __syncthreads();
#pragma unroll
    for (int j = 0; j < 32; j += 8)
      Vt[((size_t)(b * NKV + kv) * DH + dt + ty + j) * S_LEN + st + tx] = tt[tx][ty + j];
  }
}

// ---------------- causal GQA flash attention, LDS-staged K/V, 8 waves ----------------
// 512 blocks x 512 threads. Wave-group 0 (waves 0-3) -> q-tile qt=pr,
// group 1 (waves 4-7) -> q-tile 31-pr, CONCURRENT, sharing one K/V staging.
// Staged tiles nt = 32-pr; pr permuted so co-resident block pairs (wg, wg+256)
// sum to 49 steps (static balance). 2 blocks/CU -> 16 waves/CU.
__global__ __launch_bounds__(512, 4) void k_attn(const u16* __restrict__ Qr,
                                                 const u16* __restrict__ Kr,
                                                 const u16* __restrict__ Vt,
                                                 u16* __restrict__ Og) {
  __shared__ u16 kbuf[2][4096];   // [64 rows][8 chunks of 8 bf16], swizzled
  __shared__ u16 vbuf[2][4096];   // V^T: [64 d][8 chunks], swizzled
  __shared__ u16 plds[8][16][72]; // per-wave P[q16][key64], padded

  const int tid = threadIdx.x, wv = tid >> 6, lane = tid & 63;
  const int g = lane >> 4, lr = lane & 15;
  const int wg = blockIdx.x;
  const int xcd = wg & 7, iw = wg >> 3;
  const int bh = xcd * 4 + (iw & 3);
  const int j = iw >> 2;                 // 0..15
  const int pr = (j < 8) ? j : 23 - j;   // pairs (wg, wg+256): pr + pr' = 15
  const int b = bh >> 4, h = bh & 15, kv = h >> 2;
  const int qt = (wv >> 2) ? (31 - pr) : pr;
  const int q0w = qt * 64 + (wv & 3) * 16;
  const int myq = q0w + lr;
  const int myNt = qt + 1;               // my k-tile extent
  const int nt = 32 - pr;                // staged tiles = max extent

  const u16* Kbase = Kr + (size_t)(b * NKV + kv) * S_LEN * DH;
  const u16* Vbase = Vt + (size_t)(b * NKV + kv) * DH * S_LEN;

  // staging: 512 threads cover a full 64x64 tile in ONE gld16 issue each for K,V
  const int sr = tid >> 3;            // row 0..63
  const int sc = tid & 7;             // chunk-in-row
  const int ssw = sc ^ (sr & 7);      // swizzled source chunk
  const int rsw = lr & 7;             // consume-side swizzle
  u16* prow = &plds[wv][lr][0];

  const u16* Qb = Qr + ((size_t)(b * NH + h) * S_LEN + q0w) * DH;
  short8 qf0 = *(const short8*)(Qb + lr * DH + 8 * g);
  short8 qf1 = *(const short8*)(Qb + lr * DH + 32 + 8 * g);

  float m = -1e30f, l = 0.f;
  f32x4 accO[4] = {};
  const f32x4 z = {};

  // prologue: stage tile 0 into buf 0
  gld16(Kbase + (size_t)sr * DH + ssw * 8,    &kbuf[0][wv * 512]);
  gld16(Vbase + (size_t)sr * S_LEN + ssw * 8, &vbuf[0][wv * 512]);
  __syncthreads();
  int buf = 0;
  for (int ti = 0; ti < nt; ++ti) {
    const int kb = ti * 64;
    if (ti + 1 < nt) {  // prefetch next tile into other buffer
      const int kn = kb + 64;
      gld16(Kbase + (size_t)(kn + sr) * DH + ssw * 8,   &kbuf[buf ^ 1][wv * 512]);
      gld16(Vbase + (size_t)sr * S_LEN + kn + ssw * 8,  &vbuf[buf ^ 1][wv * 512]);
    }
    if (ti < myNt) {
      const u16* kl = kbuf[buf];
      const u16* vl = vbuf[buf];
      // ---- K fragments from LDS (swizzled read) ----
      short8 k0[4], k1[4];
#pragma unroll
      for (int t = 0; t < 4; ++t) {
        const int row = 16 * t + lr;
        k0[t] = *(const short8*)&kl[row * 64 + (g ^ rsw) * 8];
        k1[t] = *(const short8*)&kl[row * 64 + ((4 + g) ^ rsw) * 8];
      }
      // ---- QK^T (swapped: A=K rows=keys, B=Q cols=q) ----
      f32x4 s[4];
      __builtin_amdgcn_s_setprio(1);
#pragma unroll
      for (int t = 0; t < 4; ++t) {
        s[t] = __builtin_amdgcn_mfma_f32_16x16x32_bf16(k0[t], qf0, z, 0, 0, 0);
        s[t] = __builtin_amdgcn_mfma_f32_16x16x32_bf16(k1[t], qf1, s[t], 0, 0, 0);
      }
      __builtin_amdgcn_s_setprio(0);
      // ---- causal mask (diagonal tile only) ----
      if (kb + 63 > q0w) {
#pragma unroll
        for (int t = 0; t < 4; ++t)
#pragma unroll
          for (int r = 0; r < 4; ++r)
            if (kb + 16 * t + 4 * g + r > myq) s[t][r] = -1e30f;
      }
      // ---- online softmax (log2 domain), lane-local row ----
      float a0 = fmaxf(fmaxf(fmaxf(s[0][0], s[0][1]), s[0][2]), s[0][3]);
      float a1 = fmaxf(fmaxf(fmaxf(s[1][0], s[1][1]), s[1][2]), s[1][3]);
      float a2 = fmaxf(fmaxf(fmaxf(s[2][0], s[2][1]), s[2][2]), s[2][3]);
      float a3 = fmaxf(fmaxf(fmaxf(s[3][0], s[3][1]), s[3][2]), s[3][3]);
      float tm = fmaxf(fmaxf(a0, a1), fmaxf(a2, a3));
      tm = fmaxf(tm, __shfl_xor(tm, 16));
      tm = fmaxf(tm, __shfl_xor(tm, 32));
      if (__any(tm > m + 8.f)) {   // T13 defer-rescale
        float mn = fmaxf(tm, m);
        float al = __builtin_exp2f(m - mn);
        m = mn;
        l *= al;
#pragma unroll
        for (int t = 0; t < 4; ++t) {
          accO[t][0] *= al; accO[t][1] *= al; accO[t][2] *= al; accO[t][3] *= al;
        }
      }
      float rs = 0.f;
#pragma unroll
      for (int t = 0; t < 4; ++t)
#pragma unroll
        for (int r = 0; r < 4; ++r) {
          float e = __builtin_exp2f(s[t][r] - m);
          s[t][r] = e;
          rs += e;
        }
      rs += __shfl_xor(rs, 16);
      rs += __shfl_xor(rs, 32);
      l += rs;
      // ---- P -> LDS (row q=lr), b64 writes ----
#pragma unroll
      for (int t = 0; t < 4; ++t) {
        u32 lo = (u32)f2bf(s[t][0]) | ((u32)f2bf(s[t][1]) << 16);
        u32 hi = (u32)f2bf(s[t][2]) | ((u32)f2bf(s[t][3]) << 16);
        uint2 w2; w2.x = lo; w2.y = hi;
        *(uint2*)(prow + 16 * t + 4 * g) = w2;
      }
      // ---- PV (A=V^T rows=d, B=P^T cols=q), V from swizzled LDS ----
      short8 pb0 = *(const short8*)(prow + 8 * g);
      short8 pb1 = *(const short8*)(prow + 32 + 8 * g);
      __builtin_amdgcn_s_setprio(1);
#pragma unroll
      for (int t = 0; t < 4; ++t) {
        const int row = 16 * t + lr;
        short8 vf0 = *(const short8*)&vl[row * 64 + (g ^ rsw) * 8];
        short8 vf1 = *(const short8*)&vl[row * 64 + ((4 + g) ^ rsw) * 8];
        accO[t] = __builtin_amdgcn_mfma_f32_16x16x32_bf16(vf0, pb0, accO[t], 0, 0, 0);
        accO[t] = __builtin_amdgcn_mfma_f32_16x16x32_bf16(vf1, pb1, accO[t], 0, 0, 0);
      }
      __builtin_amdgcn_s_setprio(0);
    }
    __syncthreads();   // staged next tile arrived; all reads of buf done
    buf ^= 1;
  }

  const float inv = 1.0f / l;
  u16* orow = Og + ((size_t)(b * S_LEN + q0w + lr)) * DM + h * DH;
#pragma unroll
  for (int t = 0; t < 4; ++t) {
    ushort4 o;
    o.x = f2bf(accO[t][0] * inv);
    o.y = f2bf(accO[t][1] * inv);
    o.z = f2bf(accO[t][2] * inv);
    o.w = f2bf(accO[t][3] * inv);
    *(ushort4*)(orow + 16 * t + 4 * g) = o;
  }
}

extern "C" void kernel_launch(void* const* d_in, const int* in_sizes, int n_in,
                              void* d_out, int out_size, void* d_ws, size_t ws_size,
                              hipStream_t stream) {
  const float* x  = (const float*)d_in[0];
  const float* pe = (const float*)d_in[1];
  const float* Wq = (const float*)d_in[2];
  const float* bq = (const float*)d_in[3];
  const float* Wk = (const float*)d_in[4];
  const float* bk = (const float*)d_in[5];
  const float* Wv = (const float*)d_in[6];
  const float* bv = (const float*)d_in[7];
  const float* Wo = (const float*)d_in[8];
  const float* bo = (const float*)d_in[9];
  float* out = (float*)d_out;

  char* w = (char*)d_ws;
  u16* Xb      = (u16*)w;   w += (size_t)MROWS * DM * 2;
  u16* Wqkvt   = (u16*)w;   w += (size_t)NQKVC * DM * 2;
  u16* Wot     = (u16*)w;   w += (size_t)DM * DM * 2;
  float* biasq = (float*)w; w += NQKVC * 4;
  float* cs    = (float*)w; w += S_LEN * 32 * 4;
  float* sn    = (float*)w; w += S_LEN * 32 * 4;
  u16* QKVp    = (u16*)w;   w += (size_t)MROWS * NQKVC * 2;
  u16* Qr      = (u16*)w;   w += (size_t)B_SZ * NH * S_LEN * DH * 2;
  u16* Kr      = (u16*)w;   w += (size_t)B_SZ * NKV * S_LEN * DH * 2;
  u16* Vt      = (u16*)w;   w += (size_t)B_SZ * NKV * DH * S_LEN * 2;
  u16* Og      = (u16*)w;

  k_prep<<<3840, 256, 0, stream>>>(x, Xb, Wq, Wk, Wv, Wo, Wqkvt, Wot,
                                   bq, bk, bv, pe, biasq, cs, sn);

  k_gemm<u16><<<dim3(MROWS / 128, NQKVC / 64), 256, 0, stream>>>(
      Xb, Wqkvt, biasq, QKVp, MROWS, NQKVC, DM);

  k_rv<<<4096 + 1024, 256, 0, stream>>>(QKVp, cs, sn, Qr, Kr, Vt);

  k_attn<<<512, 512, 0, stream>>>(Qr, Kr, Vt, Og);

  k_gemm<float><<<dim3(MROWS / 128, DM / 64), 256, 0, stream>>>(
      Og, Wot, bo, out, MROWS, DM, DM);
}

// Round 15
// 176.811 us; speedup vs baseline: 1.8643x; 1.0590x over previous
//
#include <hip/hip_runtime.h>
#include <hip/hip_bf16.h>

using f32x4  = __attribute__((ext_vector_type(4))) float;
using short8 = __attribute__((ext_vector_type(8))) short;
using u16    = unsigned short;
using u32    = unsigned int;

#define B_SZ   2
#define S_LEN  2048
#define NH     16
#define NKV    4
#define DH     64
#define DM     1024
#define NQKVC  1536
#define MROWS  4096
// 0.125 * log2(e): scores computed in log2 domain, softmax via exp2
#define QSCALE 0.18033688011112042f

__device__ __forceinline__ u16 f2bf(float f) {
  return __builtin_bit_cast(u16, __float2bfloat16(f));
}
__device__ __forceinline__ float bf2f(u16 b) {
  return __builtin_bit_cast(float, ((u32)b) << 16);
}
__device__ __forceinline__ void gld16(const void* g, void* l) {
  __builtin_amdgcn_global_load_lds((const __attribute__((address_space(1))) u32*)g,
                                   (__attribute__((address_space(3))) u32*)l, 16, 0, 0);
}

// ---------------- fused prep: cast X, transpose 4 weights, bias+trig ----------------
__device__ __forceinline__ void transp_tile(const float* __restrict__ w, int ncols,
                                            u16* __restrict__ wt, int bx, int by,
                                            int tid, float (*t)[33]) {
  const int k0 = bx * 32, n0 = by * 32;
  const int tx = tid & 31, ty = tid >> 5;
#pragma unroll
  for (int j = 0; j < 32; j += 8)
    t[ty + j][tx] = w[(size_t)(k0 + ty + j) * ncols + n0 + tx];
  __syncthreads();
#pragma unroll
  for (int j = 0; j < 32; j += 8)
    wt[(size_t)(n0 + ty + j) * 1024 + k0 + tx] = f2bf(t[tx][ty + j]);
}

__global__ __launch_bounds__(256) void k_prep(
    const float* __restrict__ x, u16* __restrict__ xb,
    const float* __restrict__ Wq, const float* __restrict__ Wk,
    const float* __restrict__ Wv, const float* __restrict__ Wo,
    u16* __restrict__ Wqkvt, u16* __restrict__ Wot,
    const float* __restrict__ bq, const float* __restrict__ bk,
    const float* __restrict__ bv, const float* __restrict__ pe,
    float* __restrict__ biasqkv, float* __restrict__ cs, float* __restrict__ sn) {
  __shared__ float tt[32][33];
  const int job = blockIdx.x, tid = threadIdx.x;
  if (job < 1024) {                       // cast X fp32->bf16: 4096 floats/job
#pragma unroll
    for (int u = 0; u < 4; ++u) {
      int i = job * 4096 + u * 1024 + tid * 4;
      float4 v = *(const float4*)(x + i);
      ushort4 o;
      o.x = f2bf(v.x); o.y = f2bf(v.y); o.z = f2bf(v.z); o.w = f2bf(v.w);
      *(ushort4*)(xb + i) = o;
    }
  } else if (job < 2048) {                // Wq^T
    int t = job - 1024;
    transp_tile(Wq, 1024, Wqkvt, t & 31, t >> 5, tid, tt);
  } else if (job < 2304) {                // Wk^T
    int t = job - 2048;
    transp_tile(Wk, 256, Wqkvt + (size_t)1024 * 1024, t & 31, t >> 5, tid, tt);
  } else if (job < 2560) {                // Wv^T
    int t = job - 2304;
    transp_tile(Wv, 256, Wqkvt + (size_t)1280 * 1024, t & 31, t >> 5, tid, tt);
  } else if (job < 3584) {                // Wo^T
    int t = job - 2560;
    transp_tile(Wo, 1024, Wot, t & 31, t >> 5, tid, tt);
  } else {                                // bias concat + trig tables
    int i = (job - 3584) * 256 + tid;
    if (i < NQKVC)
      biasqkv[i] = (i < 1024) ? bq[i] : (i < 1280 ? bk[i - 1024] : bv[i - 1280]);
    float a = pe[i];
    cs[i] = cosf(a);
    sn[i] = sinf(a);
  }
}

// ---------------- bf16 MFMA GEMM, 128x64 tile, T3-min pipelined k-loop ----------------
// MODE 0: C = float out + bias (output projection)
// MODE 1: fused RoPE/pack epilogue -> Qr/Kr/Vt directly (QKV projection)
template <int MODE, typename OUT_T>
__global__ __launch_bounds__(256) void k_gemm(const u16* __restrict__ A,
                                              const u16* __restrict__ Bt,
                                              const float* __restrict__ bias,
                                              OUT_T* __restrict__ C,
                                              int M, int N, int K,
                                              const float* __restrict__ cs,
                                              const float* __restrict__ sn,
                                              u16* __restrict__ Qr,
                                              u16* __restrict__ Kr,
                                              u16* __restrict__ Vt) {
  // union: k-loop staging (la 2x8KB + lb 2x4KB = 24KB)  /  epilogue ct 128x65 f32 (33.3KB)
  __shared__ __align__(16) char smraw[33280];
  u16* laB0 = (u16*)smraw;               // la[0][4096]  rows 0..127 linear [row][32]
  u16* laB1 = (u16*)smraw + 4096;
  u16* lbB0 = (u16*)(smraw + 16384);     // lb[0][2048]
  u16* lbB1 = (u16*)(smraw + 16384) + 2048;

  const int tid = threadIdx.x;
  const int m0 = blockIdx.x * 128, n0 = blockIdx.y * 64;
  const int lane = tid & 63, wv = tid >> 6;
  const int g = lane >> 4, lr = lane & 15;
  const int wr = wv >> 1, wc = wv & 1;

  const int sr = tid >> 2;           // row 0..63
  const int scol = (tid & 3) * 8;    // u16 units
  const u16* pa0 = A  + (size_t)(m0 + sr) * K + scol;
  const u16* pa1 = A  + (size_t)(m0 + 64 + sr) * K + scol;
  const u16* pb  = Bt + (size_t)(n0 + sr) * K + scol;

  f32x4 acc[4][2] = {};
  const int nk = K >> 5;
  // prologue: stage tile 0 into buf 0
  // wave wv covers rows [wv*16, wv*16+16) at u16 offset wv*512 (= row*32 linear)
  gld16(pa0, laB0 + wv * 512);
  gld16(pa1, laB0 + 2048 + wv * 512);
  gld16(pb,  lbB0 + wv * 512);
  __syncthreads();
  for (int kt = 0; kt < nk; ++kt) {
    const u16* la = (kt & 1) ? laB1 : laB0;
    const u16* lb = (kt & 1) ? lbB1 : lbB0;
    if (kt + 1 < nk) {  // stage next tile into other buffer (overlaps compute)
      u16* lan = (kt & 1) ? laB0 : laB1;
      u16* lbn = (kt & 1) ? lbB0 : lbB1;
      const int ko = (kt + 1) * 32;
      gld16(pa0 + ko, lan + wv * 512);
      gld16(pa1 + ko, lan + 2048 + wv * 512);
      gld16(pb + ko,  lbn + wv * 512);
    }
    short8 af[4], bfr[2];
#pragma unroll
    for (int m = 0; m < 4; ++m)
      af[m] = *(const short8*)&la[(64 * wr + 16 * m + lr) * 32 + 8 * g];
#pragma unroll
    for (int n = 0; n < 2; ++n)
      bfr[n] = *(const short8*)&lb[(32 * wc + 16 * n + lr) * 32 + 8 * g];
#pragma unroll
    for (int m = 0; m < 4; ++m)
#pragma unroll
      for (int n = 0; n < 2; ++n)
        acc[m][n] = __builtin_amdgcn_mfma_f32_16x16x32_bf16(af[m], bfr[n], acc[m][n], 0, 0, 0);
    __syncthreads();  // next tile staged (vmcnt drained) + all reads of cur done
  }

  if constexpr (MODE == 0) {
#pragma unroll
    for (int m = 0; m < 4; ++m)
#pragma unroll
      for (int n = 0; n < 2; ++n) {
        const int col = n0 + 32 * wc + 16 * n + lr;
        const float bz = bias[col];
#pragma unroll
        for (int r = 0; r < 4; ++r) {
          const int row = m0 + 64 * wr + 16 * m + 4 * g + r;
          C[(size_t)row * N + col] = acc[m][n][r] + bz;
        }
      }
  } else {
    // ---- fused bias + RoPE + pack epilogue ----
    float (*ct)[65] = (float (*)[65])smraw;
#pragma unroll
    for (int m = 0; m < 4; ++m)
#pragma unroll
      for (int n = 0; n < 2; ++n) {
        const int lcol = 32 * wc + 16 * n + lr;
        const float bz = bias[n0 + lcol];
#pragma unroll
        for (int r = 0; r < 4; ++r)
          ct[64 * wr + 16 * m + 4 * g + r][lcol] = acc[m][n][r] + bz;
      }
    __syncthreads();
#pragma unroll
    for (int m = 0; m < 4; ++m)
#pragma unroll
      for (int n = 0; n < 2; ++n) {
        const int lcol = 32 * wc + 16 * n + lr;
        const int c = n0 + lcol;
        const int lr0 = 64 * wr + 16 * m + 4 * g;   // local row base (4 rows)
        const int grow0 = m0 + lr0;
        const int b = grow0 >> 11;
        const int s0 = grow0 & 2047;
        if (c < 1024) {          // Q: rope * QSCALE
          const int h = c >> 6, d = c & 63, j = d & 31;
          const float sg = (d < 32) ? -1.f : 1.f;
          u16* qp = Qr + ((size_t)(b * NH + h) * S_LEN + s0) * DH + d;
#pragma unroll
          for (int r = 0; r < 4; ++r) {
            float xv = ct[lr0 + r][lcol];
            float yv = ct[lr0 + r][lcol ^ 32];
            float o = (xv * cs[(s0 + r) * 32 + j] + sg * yv * sn[(s0 + r) * 32 + j]) * QSCALE;
            qp[(size_t)r * DH] = f2bf(o);
          }
        } else if (c < 1280) {   // K: rope
          const int cc = c - 1024, kvh = cc >> 6, d = cc & 63, j = d & 31;
          const float sg = (d < 32) ? -1.f : 1.f;
          u16* kp = Kr + ((size_t)(b * NKV + kvh) * S_LEN + s0) * DH + d;
#pragma unroll
          for (int r = 0; r < 4; ++r) {
            float xv = ct[lr0 + r][lcol];
            float yv = ct[lr0 + r][lcol ^ 32];
            float o = xv * cs[(s0 + r) * 32 + j] + sg * yv * sn[(s0 + r) * 32 + j];
            kp[(size_t)r * DH] = f2bf(o);
          }
        } else {                 // V: transpose pack -> Vt[b][kv][d][s]
          const int cc = c - 1280, kv = cc >> 6, d = cc & 63;
          ushort4 o4;
          o4.x = f2bf(ct[lr0 + 0][lcol]);
          o4.y = f2bf(ct[lr0 + 1][lcol]);
          o4.z = f2bf(ct[lr0 + 2][lcol]);
          o4.w = f2bf(ct[lr0 + 3][lcol]);
          *(ushort4*)(Vt + ((size_t)(b * NKV + kv) * DH + d) * S_LEN + s0) = o4;
        }
      }
  }
}

// ---------------- causal GQA flash attention, LDS-staged K/V, 8 waves ----------------
// 512 blocks x 512 threads. Wave-group 0 (waves 0-3) -> q-tile qt=pr,
// group 1 (waves 4-7) -> q-tile 31-pr, CONCURRENT, sharing one K/V staging.
// Staged tiles nt = 32-pr; pr permuted so co-resident block pairs (wg, wg+256)
// sum to 49 steps (static balance). 2 blocks/CU -> 16 waves/CU.
__global__ __launch_bounds__(512, 4) void k_attn(const u16* __restrict__ Qr,
                                                 const u16* __restrict__ Kr,
                                                 const u16* __restrict__ Vt,
                                                 u16* __restrict__ Og) {
  __shared__ u16 kbuf[2][4096];   // [64 rows][8 chunks of 8 bf16], swizzled
  __shared__ u16 vbuf[2][4096];   // V^T: [64 d][8 chunks], swizzled
  __shared__ u16 plds[8][16][72]; // per-wave P[q16][key64], padded

  const int tid = threadIdx.x, wv = tid >> 6, lane = tid & 63;
  const int g = lane >> 4, lr = lane & 15;
  const int wg = blockIdx.x;
  const int xcd = wg & 7, iw = wg >> 3;
  const int bh = xcd * 4 + (iw & 3);
  const int j = iw >> 2;                 // 0..15
  const int pr = (j < 8) ? j : 23 - j;   // pairs (wg, wg+256): pr + pr' = 15
  const int b = bh >> 4, h = bh & 15, kv = h >> 2;
  const int qt = (wv >> 2) ? (31 - pr) : pr;
  const int q0w = qt * 64 + (wv & 3) * 16;
  const int myq = q0w + lr;
  const int myNt = qt + 1;               // my k-tile extent
  const int nt = 32 - pr;                // staged tiles = max extent

  const u16* Kbase = Kr + (size_t)(b * NKV + kv) * S_LEN * DH;
  const u16* Vbase = Vt + (size_t)(b * NKV + kv) * DH * S_LEN;

  // staging: 512 threads cover a full 64x64 tile in ONE gld16 issue each for K,V
  const int sr = tid >> 3;            // row 0..63
  const int sc = tid & 7;             // chunk-in-row
  const int ssw = sc ^ (sr & 7);      // swizzled source chunk
  const int rsw = lr & 7;             // consume-side swizzle
  u16* prow = &plds[wv][lr][0];

  const u16* Qb = Qr + ((size_t)(b * NH + h) * S_LEN + q0w) * DH;
  short8 qf0 = *(const short8*)(Qb + lr * DH + 8 * g);
  short8 qf1 = *(const short8*)(Qb + lr * DH + 32 + 8 * g);

  float m = -1e30f, l = 0.f;
  f32x4 accO[4] = {};
  const f32x4 z = {};

  // prologue: stage tile 0 into buf 0
  gld16(Kbase + (size_t)sr * DH + ssw * 8,    &kbuf[0][wv * 512]);
  gld16(Vbase + (size_t)sr * S_LEN + ssw * 8, &vbuf[0][wv * 512]);
  __syncthreads();
  int buf = 0;
  for (int ti = 0; ti < nt; ++ti) {
    const int kb = ti * 64;
    if (ti + 1 < nt) {  // prefetch next tile into other buffer
      const int kn = kb + 64;
      gld16(Kbase + (size_t)(kn + sr) * DH + ssw * 8,   &kbuf[buf ^ 1][wv * 512]);
      gld16(Vbase + (size_t)sr * S_LEN + kn + ssw * 8,  &vbuf[buf ^ 1][wv * 512]);
    }
    if (ti < myNt) {
      const u16* kl = kbuf[buf];
      const u16* vl = vbuf[buf];
      // ---- K fragments from LDS (swizzled read) ----
      short8 k0[4], k1[4];
#pragma unroll
      for (int t = 0; t < 4; ++t) {
        const int row = 16 * t + lr;
        k0[t] = *(const short8*)&kl[row * 64 + (g ^ rsw) * 8];
        k1[t] = *(const short8*)&kl[row * 64 + ((4 + g) ^ rsw) * 8];
      }
      // ---- QK^T (swapped: A=K rows=keys, B=Q cols=q) ----
      f32x4 s[4];
      __builtin_amdgcn_s_setprio(1);
#pragma unroll
      for (int t = 0; t < 4; ++t) {
        s[t] = __builtin_amdgcn_mfma_f32_16x16x32_bf16(k0[t], qf0, z, 0, 0, 0);
        s[t] = __builtin_amdgcn_mfma_f32_16x16x32_bf16(k1[t], qf1, s[t], 0, 0, 0);
      }
      __builtin_amdgcn_s_setprio(0);
      // ---- causal mask (diagonal tile only) ----
      if (kb + 63 > q0w) {
#pragma unroll
        for (int t = 0; t < 4; ++t)
#pragma unroll
          for (int r = 0; r < 4; ++r)
            if (kb + 16 * t + 4 * g + r > myq) s[t][r] = -1e30f;
      }
      // ---- online softmax (log2 domain), lane-local row ----
      float a0 = fmaxf(fmaxf(fmaxf(s[0][0], s[0][1]), s[0][2]), s[0][3]);
      float a1 = fmaxf(fmaxf(fmaxf(s[1][0], s[1][1]), s[1][2]), s[1][3]);
      float a2 = fmaxf(fmaxf(fmaxf(s[2][0], s[2][1]), s[2][2]), s[2][3]);
      float a3 = fmaxf(fmaxf(fmaxf(s[3][0], s[3][1]), s[3][2]), s[3][3]);
      float tm = fmaxf(fmaxf(a0, a1), fmaxf(a2, a3));
      tm = fmaxf(tm, __shfl_xor(tm, 16));
      tm = fmaxf(tm, __shfl_xor(tm, 32));
      if (__any(tm > m + 8.f)) {   // T13 defer-rescale
        float mn = fmaxf(tm, m);
        float al = __builtin_exp2f(m - mn);
        m = mn;
        l *= al;
#pragma unroll
        for (int t = 0; t < 4; ++t) {
          accO[t][0] *= al; accO[t][1] *= al; accO[t][2] *= al; accO[t][3] *= al;
        }
      }
      float rs = 0.f;
#pragma unroll
      for (int t = 0; t < 4; ++t)
#pragma unroll
        for (int r = 0; r < 4; ++r) {
          float e = __builtin_exp2f(s[t][r] - m);
          s[t][r] = e;
          rs += e;
        }
      rs += __shfl_xor(rs, 16);
      rs += __shfl_xor(rs, 32);
      l += rs;
      // ---- P -> LDS (row q=lr), b64 writes ----
#pragma unroll
      for (int t = 0; t < 4; ++t) {
        u32 lo = (u32)f2bf(s[t][0]) | ((u32)f2bf(s[t][1]) << 16);
        u32 hi = (u32)f2bf(s[t][2]) | ((u32)f2bf(s[t][3]) << 16);
        uint2 w2; w2.x = lo; w2.y = hi;
        *(uint2*)(prow + 16 * t + 4 * g) = w2;
      }
      // ---- PV (A=V^T rows=d, B=P^T cols=q), V from swizzled LDS ----
      short8 pb0 = *(const short8*)(prow + 8 * g);
      short8 pb1 = *(const short8*)(prow + 32 + 8 * g);
      __builtin_amdgcn_s_setprio(1);
#pragma unroll
      for (int t = 0; t < 4; ++t) {
        const int row = 16 * t + lr;
        short8 vf0 = *(const short8*)&vl[row * 64 + (g ^ rsw) * 8];
        short8 vf1 = *(const short8*)&vl[row * 64 + ((4 + g) ^ rsw) * 8];
        accO[t] = __builtin_amdgcn_mfma_f32_16x16x32_bf16(vf0, pb0, accO[t], 0, 0, 0);
        accO[t] = __builtin_amdgcn_mfma_f32_16x16x32_bf16(vf1, pb1, accO[t], 0, 0, 0);
      }
      __builtin_amdgcn_s_setprio(0);
    }
    __syncthreads();   // staged next tile arrived; all reads of buf done
    buf ^= 1;
  }

  const float inv = 1.0f / l;
  u16* orow = Og + ((size_t)(b * S_LEN + q0w + lr)) * DM + h * DH;
#pragma unroll
  for (int t = 0; t < 4; ++t) {
    ushort4 o;
    o.x = f2bf(accO[t][0] * inv);
    o.y = f2bf(accO[t][1] * inv);
    o.z = f2bf(accO[t][2] * inv);
    o.w = f2bf(accO[t][3] * inv);
    *(ushort4*)(orow + 16 * t + 4 * g) = o;
  }
}

extern "C" void kernel_launch(void* const* d_in, const int* in_sizes, int n_in,
                              void* d_out, int out_size, void* d_ws, size_t ws_size,
                              hipStream_t stream) {
  const float* x  = (const float*)d_in[0];
  const float* pe = (const float*)d_in[1];
  const float* Wq = (const float*)d_in[2];
  const float* bq = (const float*)d_in[3];
  const float* Wk = (const float*)d_in[4];
  const float* bk = (const float*)d_in[5];
  const float* Wv = (const float*)d_in[6];
  const float* bv = (const float*)d_in[7];
  const float* Wo = (const float*)d_in[8];
  const float* bo = (const float*)d_in[9];
  float* out = (float*)d_out;

  char* w = (char*)d_ws;
  u16* Xb      = (u16*)w;   w += (size_t)MROWS * DM * 2;
  u16* Wqkvt   = (u16*)w;   w += (size_t)NQKVC * DM * 2;
  u16* Wot     = (u16*)w;   w += (size_t)DM * DM * 2;
  float* biasq = (float*)w; w += NQKVC * 4;
  float* cs    = (float*)w; w += S_LEN * 32 * 4;
  float* sn    = (float*)w; w += S_LEN * 32 * 4;
  u16* Qr      = (u16*)w;   w += (size_t)B_SZ * NH * S_LEN * DH * 2;
  u16* Kr      = (u16*)w;   w += (size_t)B_SZ * NKV * S_LEN * DH * 2;
  u16* Vt      = (u16*)w;   w += (size_t)B_SZ * NKV * DH * S_LEN * 2;
  u16* Og      = (u16*)w;

  k_prep<<<3840, 256, 0, stream>>>(x, Xb, Wq, Wk, Wv, Wo, Wqkvt, Wot,
                                   bq, bk, bv, pe, biasq, cs, sn);

  // QKV projection with fused bias+RoPE+pack epilogue
  k_gemm<1, u16><<<dim3(MROWS / 128, NQKVC / 64), 256, 0, stream>>>(
      Xb, Wqkvt, biasq, (u16*)nullptr, MROWS, NQKVC, DM, cs, sn, Qr, Kr, Vt);

  k_attn<<<512, 512, 0, stream>>>(Qr, Kr, Vt, Og);

  // output projection
  k_gemm<0, float><<<dim3(MROWS / 128, DM / 64), 256, 0, stream>>>(
      Og, Wot, bo, out, MROWS, DM, DM, nullptr, nullptr, nullptr, nullptr, nullptr);
}